// Round 1
// baseline (1449.359 us; speedup 1.0000x reference)
//
#include <hip/hip_runtime.h>
#include <hip/hip_bf16.h>

#define NN 1024
#define DD 8

// ---------------- workspace layout (floats) ----------------
// PH    : [896][1024][8]   offset 0         count 7340032   (zero-init per call)
// Uin   : [64][1024][8]    7340032          524288
// Utop  : [64][1024][8]    7864320          524288          (tick1 hidden upd, rows<64)
// Uright: [896][64][8]     8388608          458752          (tick1 hidden upd, cols>=960)
// Uout  : [64][1024][8]    8847360          524288
// P     : [1024][8]        9371648          8192
// Spart : [8][1024][8]     9379840          65536
// total 9445376 floats = 37,781,504 bytes

__device__ __forceinline__ void gru_upd(const float* __restrict__ sW,
                                        const float pre[8], const float post[8],
                                        const float h[8], float reward, float lr,
                                        float upd[8])
{
    // sW: [0..407]=Wih(24x17), [408..599]=Whh(24x8), [600..623]=Bih, [624..647]=Bhh
    const float* Wih = sW;
    const float* Whh = sW + 408;
    const float* Bih = sW + 600;
    const float* Bhh = sW + 624;
    float gx[24], gh[24];
#pragma unroll
    for (int j = 0; j < 24; ++j) {
        const float* w = Wih + j * 17;
        float a = Bih[j] + w[16] * reward;
#pragma unroll
        for (int d = 0; d < 8; ++d) a += w[d] * pre[d];
#pragma unroll
        for (int d = 0; d < 8; ++d) a += w[8 + d] * post[d];
        gx[j] = a;
        const float* wh = Whh + j * 8;
        float b = Bhh[j];
#pragma unroll
        for (int d = 0; d < 8; ++d) b += wh[d] * h[d];
        gh[j] = b;
    }
#pragma unroll
    for (int d = 0; d < 8; ++d) {
        float r  = 1.f / (1.f + expf(-(gx[d] + gh[d])));
        float z  = 1.f / (1.f + expf(-(gx[8 + d] + gh[8 + d])));
        float nn = tanhf(gx[16 + d] + r * gh[16 + d]);
        float g  = (1.f - z) * nn + z * h[d];
        upd[d] = h[d] + g * lr;
    }
}

#define STAGE_W()                                                                      \
    __shared__ float sW[648];                                                          \
    for (int i = threadIdx.x; i < 648; i += blockDim.x)                                \
        sW[i] = (i < 408) ? Wih[i] : (i < 600) ? Whh[i - 408]                          \
                          : (i < 624) ? Bih[i - 600] : Bhh[i - 624];                   \
    __syncthreads();

__global__ void k_init(float4* __restrict__ PH4, float* __restrict__ P,
                       const float* __restrict__ post0)
{
    const int nph4 = 7340032 / 4;
    int stride = gridDim.x * blockDim.x;
    int gid = blockIdx.x * blockDim.x + threadIdx.x;
    float4 z; z.x = z.y = z.z = z.w = 0.f;
    for (int i = gid; i < nph4; i += stride) PH4[i] = z;
    if (gid < 8192) P[gid] = post0[gid];
}

__global__ void k_inp(const float* __restrict__ obs, const float* __restrict__ W,
                      const float* __restrict__ b, float* __restrict__ P)
{
    int t = threadIdx.x;           // 512 = 64 neurons x 8 dims
    int i = t >> 3, j = t & 7;
    float rs = 0.f;
#pragma unroll
    for (int d = 0; d < 8; ++d) rs += W[j * 8 + d];
    P[i * 8 + j] = tanhf(obs[i] * rs + b[j]);
}

// input-layer synapses: rows r in [0,64), all cols, mask A[r][n]
template <int TICK>
__global__ void k_syn_in(const int* __restrict__ A, const float* __restrict__ hidden0,
                         const float* __restrict__ P, float* __restrict__ PH,
                         float* __restrict__ Uin, const float* __restrict__ Utop,
                         const float* __restrict__ Uout,
                         const float* __restrict__ Wih, const float* __restrict__ Whh,
                         const float* __restrict__ Bih, const float* __restrict__ Bhh,
                         const float* __restrict__ reward, const float* __restrict__ lr)
{
    STAGE_W();
    int gid = blockIdx.x * blockDim.x + threadIdx.x;
    int r = gid >> 10, n = gid & 1023;
    if (!A[r * NN + n]) return;
    float pre[8], post[8], h[8], upd[8];
#pragma unroll
    for (int d = 0; d < 8; ++d) pre[d] = P[r * 8 + d];
#pragma unroll
    for (int d = 0; d < 8; ++d) post[d] = P[n * 8 + d];
    int e = (r * NN + n) * 8;
    if (TICK == 1) {
#pragma unroll
        for (int d = 0; d < 8; ++d) h[d] = hidden0[e + d];
    } else {
        const float* src;
        if (A[(960 + r) * NN + n])      src = Uout + e;
        else if (A[(64 + r) * NN + n])  src = Utop + e;
        else                            src = Uin + e;
#pragma unroll
        for (int d = 0; d < 8; ++d) h[d] = src[d];
    }
    gru_upd(sW, pre, post, h, reward[0], lr[0], upd);
#pragma unroll
    for (int d = 0; d < 8; ++d) PH[e + d] = upd[d] * pre[d];
    if (TICK == 1) {
#pragma unroll
        for (int d = 0; d < 8; ++d) Uin[e + d] = upd[d];
    }
}

// hidden-layer synapses tick1: l in [0,896), all cols, mask A[64+l][n]
__global__ void k_syn_hid1(const int* __restrict__ A, const float* __restrict__ hidden0,
                           const float* __restrict__ P, float* __restrict__ PH,
                           float* __restrict__ Utop, float* __restrict__ Uright,
                           const float* __restrict__ Wih, const float* __restrict__ Whh,
                           const float* __restrict__ Bih, const float* __restrict__ Bhh,
                           const float* __restrict__ reward, const float* __restrict__ lr)
{
    STAGE_W();
    int gid = blockIdx.x * blockDim.x + threadIdx.x;
    int l = gid >> 10, n = gid & 1023;
    if (!A[(64 + l) * NN + n]) return;
    float pre[8], post[8], h[8], upd[8];
#pragma unroll
    for (int d = 0; d < 8; ++d) pre[d] = P[(64 + l) * 8 + d];
#pragma unroll
    for (int d = 0; d < 8; ++d) post[d] = P[n * 8 + d];
    int eh = ((64 + l) * NN + n) * 8;
#pragma unroll
    for (int d = 0; d < 8; ++d) h[d] = hidden0[eh + d];
    gru_upd(sW, pre, post, h, reward[0], lr[0], upd);
    int e = (l * NN + n) * 8;
#pragma unroll
    for (int d = 0; d < 8; ++d) PH[e + d] = upd[d] * pre[d];
    if (l < 64) {
#pragma unroll
        for (int d = 0; d < 8; ++d) Utop[e + d] = upd[d];
    }
    if (n >= 960) {
        int er = (l * 64 + (n - 960)) * 8;
#pragma unroll
        for (int d = 0; d < 8; ++d) Uright[er + d] = upd[d];
    }
}

// hidden-layer synapses tick2: only cols n in [960,1024) matter afterwards
__global__ void k_syn_hid2(const int* __restrict__ A, const float* __restrict__ hidden0,
                           const float* __restrict__ P, float* __restrict__ PH,
                           const float* __restrict__ Uright,
                           const float* __restrict__ Wih, const float* __restrict__ Whh,
                           const float* __restrict__ Bih, const float* __restrict__ Bhh,
                           const float* __restrict__ reward, const float* __restrict__ lr)
{
    STAGE_W();
    int gid = blockIdx.x * blockDim.x + threadIdx.x;
    int l = gid >> 6, nn = gid & 63, n = 960 + nn;
    if (!A[(64 + l) * NN + n]) return;
    float pre[8], post[8], h[8], upd[8];
#pragma unroll
    for (int d = 0; d < 8; ++d) pre[d] = P[(64 + l) * 8 + d];
#pragma unroll
    for (int d = 0; d < 8; ++d) post[d] = P[n * 8 + d];
    // h = H[64+l][n] after tick1
    const float* hp;
    if (l < 832 && A[(128 + l) * NN + n]) hp = Uright + ((64 + l) * 64 + nn) * 8;
    else                                  hp = hidden0 + ((64 + l) * NN + n) * 8;
#pragma unroll
    for (int d = 0; d < 8; ++d) h[d] = hp[d];
    gru_upd(sW, pre, post, h, reward[0], lr[0], upd);
    int e = (l * NN + n) * 8;
#pragma unroll
    for (int d = 0; d < 8; ++d) PH[e + d] = upd[d] * pre[d];
}

// output-layer synapses (tick1 only): rows 960+l, mask A[960+l][n]
__global__ void k_syn_out(const int* __restrict__ A, const float* __restrict__ hidden0,
                          const float* __restrict__ P, float* __restrict__ PH,
                          float* __restrict__ Uout,
                          const float* __restrict__ Wih, const float* __restrict__ Whh,
                          const float* __restrict__ Bih, const float* __restrict__ Bhh,
                          const float* __restrict__ reward, const float* __restrict__ lr)
{
    STAGE_W();
    int gid = blockIdx.x * blockDim.x + threadIdx.x;
    int l = gid >> 10, n = gid & 1023;
    if (!A[(960 + l) * NN + n]) return;
    float pre[8], post[8], h[8], upd[8];
#pragma unroll
    for (int d = 0; d < 8; ++d) pre[d] = P[(960 + l) * 8 + d];
#pragma unroll
    for (int d = 0; d < 8; ++d) post[d] = P[n * 8 + d];
    int eh = ((960 + l) * NN + n) * 8;
#pragma unroll
    for (int d = 0; d < 8; ++d) h[d] = hidden0[eh + d];
    gru_upd(sW, pre, post, h, reward[0], lr[0], upd);
    int e = (l * NN + n) * 8;
#pragma unroll
    for (int d = 0; d < 8; ++d) PH[e + d] = upd[d] * pre[d];
#pragma unroll
    for (int d = 0; d < 8; ++d) Uout[e + d] = upd[d];
}

// partial column sums over PH: grid (ncolgroups, 8 rowblocks), 256 thr = 32 cols x 8 dims
__global__ void k_colsum(const float* __restrict__ PH, float* __restrict__ Spart,
                         int col_start, int rows_per_block)
{
    int base = (col_start + blockIdx.x * 32) * 8 + threadIdx.x;
    int r0 = blockIdx.y * rows_per_block;
    float acc = 0.f;
    for (int k = 0; k < rows_per_block; ++k)
        acc += PH[(r0 + k) * 8192 + base];
    Spart[blockIdx.y * 8192 + base] = acc;
}

// neuron update: P[col] = tanh( (sum_rb Spart) @ W.T + b )
__global__ void k_neuron(const float* __restrict__ Spart, float* __restrict__ P,
                         const float* __restrict__ W, const float* __restrict__ b,
                         int col_start)
{
    int gid = blockIdx.x * blockDim.x + threadIdx.x;
    int nl = gid >> 3, j = gid & 7;
    int col = col_start + nl;
    float S[8];
#pragma unroll
    for (int d = 0; d < 8; ++d) {
        float a = 0.f;
#pragma unroll
        for (int rb = 0; rb < 8; ++rb) a += Spart[rb * 8192 + col * 8 + d];
        S[d] = a;
    }
    float z = b[j];
#pragma unroll
    for (int d = 0; d < 8; ++d) z += S[d] * W[j * 8 + d];
    P[col * 8 + j] = tanhf(z);
}

__global__ void k_argmax(const float* __restrict__ P, float* __restrict__ out)
{
    __shared__ float v[64];
    int t = threadIdx.x;
    if (t < 64) v[t] = P[(960 + t) * 8];  // dim 0 of output neurons
    __syncthreads();
    if (t == 0) {
        int best = 0; float bv = v[0];
        for (int j = 1; j < 64; ++j)
            if (v[j] > bv) { bv = v[j]; best = j; }   // strict > = first-index tie-break
        out[0] = (float)best;
    }
}

extern "C" void kernel_launch(void* const* d_in, const int* in_sizes, int n_in,
                              void* d_out, int out_size, void* d_ws, size_t ws_size,
                              hipStream_t stream)
{
    const float* obs      = (const float*)d_in[0];
    const float* reward   = (const float*)d_in[1];
    const int*   A        = (const int*)d_in[2];
    const float* hidden0  = (const float*)d_in[3];
    const float* post0    = (const float*)d_in[4];
    const float* lr       = (const float*)d_in[5];
    const float* fc_in_w  = (const float*)d_in[6];
    const float* fc_in_b  = (const float*)d_in[7];
    const float* fc_hid_w = (const float*)d_in[8];
    const float* fc_hid_b = (const float*)d_in[9];
    const float* fc_out_w = (const float*)d_in[10];
    const float* fc_out_b = (const float*)d_in[11];
    const float* gin_wih  = (const float*)d_in[12];
    const float* gin_whh  = (const float*)d_in[13];
    const float* gin_bih  = (const float*)d_in[14];
    const float* gin_bhh  = (const float*)d_in[15];
    const float* ghid_wih = (const float*)d_in[16];
    const float* ghid_whh = (const float*)d_in[17];
    const float* ghid_bih = (const float*)d_in[18];
    const float* ghid_bhh = (const float*)d_in[19];
    const float* gout_wih = (const float*)d_in[20];
    const float* gout_whh = (const float*)d_in[21];
    const float* gout_bih = (const float*)d_in[22];
    const float* gout_bhh = (const float*)d_in[23];

    float* ws    = (float*)d_ws;
    float* PH    = ws;
    float* Uin   = ws + 7340032;
    float* Utop  = Uin + 524288;
    float* Urt   = Utop + 524288;
    float* Uout  = Urt + 458752;
    float* P     = Uout + 524288;
    float* Spart = P + 8192;

    k_init<<<2048, 256, 0, stream>>>((float4*)PH, P, post0);
    k_inp<<<1, 512, 0, stream>>>(obs, fc_in_w, fc_in_b, P);

    // ---- tick 1 ----
    k_syn_in<1><<<256, 256, 0, stream>>>(A, hidden0, P, PH, Uin, Utop, Uout,
                                         gin_wih, gin_whh, gin_bih, gin_bhh, reward, lr);
    k_colsum<<<dim3(28, 8), 256, 0, stream>>>(PH, Spart, 64, 8);    // only rows<64 written yet
    k_neuron<<<28, 256, 0, stream>>>(Spart, P, fc_hid_w, fc_hid_b, 64);
    k_syn_hid1<<<3584, 256, 0, stream>>>(A, hidden0, P, PH, Utop, Urt,
                                         ghid_wih, ghid_whh, ghid_bih, ghid_bhh, reward, lr);
    k_colsum<<<dim3(2, 8), 256, 0, stream>>>(PH, Spart, 960, 112);
    k_neuron<<<2, 256, 0, stream>>>(Spart, P, fc_out_w, fc_out_b, 960);
    k_syn_out<<<256, 256, 0, stream>>>(A, hidden0, P, PH, Uout,
                                       gout_wih, gout_whh, gout_bih, gout_bhh, reward, lr);

    // ---- tick 2 (input-neuron update identical to tick1 -> skipped; out-syn dead) ----
    k_syn_in<2><<<256, 256, 0, stream>>>(A, hidden0, P, PH, Uin, Utop, Uout,
                                         gin_wih, gin_whh, gin_bih, gin_bhh, reward, lr);
    k_colsum<<<dim3(28, 8), 256, 0, stream>>>(PH, Spart, 64, 112);
    k_neuron<<<28, 256, 0, stream>>>(Spart, P, fc_hid_w, fc_hid_b, 64);
    k_syn_hid2<<<224, 256, 0, stream>>>(A, hidden0, P, PH, Urt,
                                        ghid_wih, ghid_whh, ghid_bih, ghid_bhh, reward, lr);
    k_colsum<<<dim3(2, 8), 256, 0, stream>>>(PH, Spart, 960, 112);
    k_neuron<<<2, 256, 0, stream>>>(Spart, P, fc_out_w, fc_out_b, 960);

    k_argmax<<<1, 64, 0, stream>>>(P, (float*)d_out);
}

// Round 2
// 539.598 us; speedup vs baseline: 2.6860x; 2.6860x over previous
//
#include <hip/hip_runtime.h>
#include <hip/hip_bf16.h>

#define NN 1024
#define DD 8

// ---------------- workspace layout (floats) ----------------
// PH    : [896][1024][8]   offset 0         count 7340032   (zero-init per call)
// Uin   : [64][1024][8]    7340032          524288
// Utop  : [64][1024][8]    7864320          524288          (tick1 hidden upd, rows<64)
// Uright: [896][64][8]     8388608          458752          (tick1 hidden upd, cols>=960)
// Uout  : [64][1024][8]    8847360          524288
// P     : [1024][8]        9371648          8192
// Spart : [8][1024][8]     9379840          65536

__device__ __forceinline__ float gate_x(const float* __restrict__ sW, int j,
                                        const float* pre, const float* post, float reward)
{
    const float* w = sW + j * 17;            // Wih row j (17 wide)
    float a = sW[600 + j] + w[16] * reward;  // Bih[j] + reward term
#pragma unroll
    for (int d = 0; d < 8; ++d) a += w[d] * pre[d];
#pragma unroll
    for (int d = 0; d < 8; ++d) a += w[8 + d] * post[d];
    return a;
}

__device__ __forceinline__ float gate_h(const float* __restrict__ sW, int j, const float* h)
{
    const float* wh = sW + 408 + j * 8;      // Whh row j
    float b = sW[624 + j];                   // Bhh[j]
#pragma unroll
    for (int d = 0; d < 8; ++d) b += wh[d] * h[d];
    return b;
}

// No gx[24]/gh[24] arrays: per output dim d, compute gates for rows d, 8+d, 16+d
// and consume immediately. Live state ~45 VGPRs, all statically indexed.
__device__ __forceinline__ void gru_upd(const float* __restrict__ sW,
                                        const float pre[8], const float post[8],
                                        const float h[8], float reward, float lr,
                                        float upd[8])
{
#pragma unroll
    for (int d = 0; d < 8; ++d) {
        float xr = gate_x(sW, d, pre, post, reward);
        float hr = gate_h(sW, d, h);
        float xz = gate_x(sW, 8 + d, pre, post, reward);
        float hz = gate_h(sW, 8 + d, h);
        float xn = gate_x(sW, 16 + d, pre, post, reward);
        float hn = gate_h(sW, 16 + d, h);
        float r  = 1.f / (1.f + expf(-(xr + hr)));
        float z  = 1.f / (1.f + expf(-(xz + hz)));
        float nn = tanhf(xn + r * hn);
        float g  = (1.f - z) * nn + z * h[d];
        upd[d] = h[d] + g * lr;
    }
}

#define STAGE_W()                                                                      \
    __shared__ float sW[648];                                                          \
    for (int i = threadIdx.x; i < 648; i += blockDim.x)                                \
        sW[i] = (i < 408) ? Wih[i] : (i < 600) ? Whh[i - 408]                          \
                          : (i < 624) ? Bih[i - 600] : Bhh[i - 624];                   \
    __syncthreads();

#define LD8(dst, src)                                                                  \
    { *(float4*)&(dst)[0] = *(const float4*)&(src)[0];                                 \
      *(float4*)&(dst)[4] = *(const float4*)&(src)[4]; }
#define ST8(dst, src)                                                                  \
    { *(float4*)&(dst)[0] = *(const float4*)&(src)[0];                                 \
      *(float4*)&(dst)[4] = *(const float4*)&(src)[4]; }

__global__ void k_init(float4* __restrict__ PH4, float* __restrict__ P,
                       const float* __restrict__ post0)
{
    const int nph4 = 7340032 / 4;
    int stride = gridDim.x * blockDim.x;
    int gid = blockIdx.x * blockDim.x + threadIdx.x;
    float4 z; z.x = z.y = z.z = z.w = 0.f;
    for (int i = gid; i < nph4; i += stride) PH4[i] = z;
    if (gid < 8192) P[gid] = post0[gid];
}

__global__ void k_inp(const float* __restrict__ obs, const float* __restrict__ W,
                      const float* __restrict__ b, float* __restrict__ P)
{
    int t = threadIdx.x;           // 512 = 64 neurons x 8 dims
    int i = t >> 3, j = t & 7;
    float rs = 0.f;
#pragma unroll
    for (int d = 0; d < 8; ++d) rs += W[j * 8 + d];
    P[i * 8 + j] = tanhf(obs[i] * rs + b[j]);
}

// input-layer synapses: rows r in [0,64), all cols, mask A[r][n]
template <int TICK>
__global__ void k_syn_in(const int* __restrict__ A, const float* __restrict__ hidden0,
                         const float* __restrict__ P, float* __restrict__ PH,
                         float* __restrict__ Uin, const float* __restrict__ Utop,
                         const float* __restrict__ Uout,
                         const float* __restrict__ Wih, const float* __restrict__ Whh,
                         const float* __restrict__ Bih, const float* __restrict__ Bhh,
                         const float* __restrict__ reward, const float* __restrict__ lr)
{
    STAGE_W();
    int gid = blockIdx.x * blockDim.x + threadIdx.x;
    int r = gid >> 10, n = gid & 1023;
    if (!A[r * NN + n]) return;
    float pre[8], post[8], h[8], upd[8];
    LD8(pre, P + r * 8);
    LD8(post, P + n * 8);
    int e = (r * NN + n) * 8;
    if (TICK == 1) {
        LD8(h, hidden0 + e);
    } else {
        const float* src;
        if (A[(960 + r) * NN + n])      src = Uout + e;
        else if (A[(64 + r) * NN + n])  src = Utop + e;
        else                            src = Uin + e;
        LD8(h, src);
    }
    gru_upd(sW, pre, post, h, reward[0], lr[0], upd);
    float out[8];
#pragma unroll
    for (int d = 0; d < 8; ++d) out[d] = upd[d] * pre[d];
    ST8(PH + e, out);
    if (TICK == 1) ST8(Uin + e, upd);
}

// hidden-layer synapses tick1: l in [0,896), all cols, mask A[64+l][n]
__global__ void k_syn_hid1(const int* __restrict__ A, const float* __restrict__ hidden0,
                           const float* __restrict__ P, float* __restrict__ PH,
                           float* __restrict__ Utop, float* __restrict__ Uright,
                           const float* __restrict__ Wih, const float* __restrict__ Whh,
                           const float* __restrict__ Bih, const float* __restrict__ Bhh,
                           const float* __restrict__ reward, const float* __restrict__ lr)
{
    STAGE_W();
    int gid = blockIdx.x * blockDim.x + threadIdx.x;
    int l = gid >> 10, n = gid & 1023;
    if (!A[(64 + l) * NN + n]) return;
    float pre[8], post[8], h[8], upd[8];
    LD8(pre, P + (64 + l) * 8);
    LD8(post, P + n * 8);
    int eh = ((64 + l) * NN + n) * 8;
    LD8(h, hidden0 + eh);
    gru_upd(sW, pre, post, h, reward[0], lr[0], upd);
    int e = (l * NN + n) * 8;
    float out[8];
#pragma unroll
    for (int d = 0; d < 8; ++d) out[d] = upd[d] * pre[d];
    ST8(PH + e, out);
    if (l < 64) ST8(Utop + e, upd);
    if (n >= 960) {
        int er = (l * 64 + (n - 960)) * 8;
        ST8(Uright + er, upd);
    }
}

// hidden-layer synapses tick2: only cols n in [960,1024) matter afterwards
__global__ void k_syn_hid2(const int* __restrict__ A, const float* __restrict__ hidden0,
                           const float* __restrict__ P, float* __restrict__ PH,
                           const float* __restrict__ Uright,
                           const float* __restrict__ Wih, const float* __restrict__ Whh,
                           const float* __restrict__ Bih, const float* __restrict__ Bhh,
                           const float* __restrict__ reward, const float* __restrict__ lr)
{
    STAGE_W();
    int gid = blockIdx.x * blockDim.x + threadIdx.x;
    int l = gid >> 6, nn = gid & 63, n = 960 + nn;
    if (!A[(64 + l) * NN + n]) return;
    float pre[8], post[8], h[8], upd[8];
    LD8(pre, P + (64 + l) * 8);
    LD8(post, P + n * 8);
    // h = H[64+l][n] after tick1
    const float* hp;
    if (l < 832 && A[(128 + l) * NN + n]) hp = Uright + ((64 + l) * 64 + nn) * 8;
    else                                  hp = hidden0 + ((64 + l) * NN + n) * 8;
    LD8(h, hp);
    gru_upd(sW, pre, post, h, reward[0], lr[0], upd);
    int e = (l * NN + n) * 8;
    float out[8];
#pragma unroll
    for (int d = 0; d < 8; ++d) out[d] = upd[d] * pre[d];
    ST8(PH + e, out);
}

// output-layer synapses (tick1 only): rows 960+l, mask A[960+l][n]
__global__ void k_syn_out(const int* __restrict__ A, const float* __restrict__ hidden0,
                          const float* __restrict__ P, float* __restrict__ PH,
                          float* __restrict__ Uout,
                          const float* __restrict__ Wih, const float* __restrict__ Whh,
                          const float* __restrict__ Bih, const float* __restrict__ Bhh,
                          const float* __restrict__ reward, const float* __restrict__ lr)
{
    STAGE_W();
    int gid = blockIdx.x * blockDim.x + threadIdx.x;
    int l = gid >> 10, n = gid & 1023;
    if (!A[(960 + l) * NN + n]) return;
    float pre[8], post[8], h[8], upd[8];
    LD8(pre, P + (960 + l) * 8);
    LD8(post, P + n * 8);
    int eh = ((960 + l) * NN + n) * 8;
    LD8(h, hidden0 + eh);
    gru_upd(sW, pre, post, h, reward[0], lr[0], upd);
    int e = (l * NN + n) * 8;
    float out[8];
#pragma unroll
    for (int d = 0; d < 8; ++d) out[d] = upd[d] * pre[d];
    ST8(PH + e, out);
    ST8(Uout + e, upd);
}

// partial column sums over PH: grid (ncolgroups, 8 rowblocks), 256 thr = 32 cols x 8 dims
__global__ void k_colsum(const float* __restrict__ PH, float* __restrict__ Spart,
                         int col_start, int rows_per_block)
{
    int base = (col_start + blockIdx.x * 32) * 8 + threadIdx.x;
    int r0 = blockIdx.y * rows_per_block;
    float acc = 0.f;
    for (int k = 0; k < rows_per_block; ++k)
        acc += PH[(r0 + k) * 8192 + base];
    Spart[blockIdx.y * 8192 + base] = acc;
}

// neuron update: P[col] = tanh( (sum_rb Spart) @ W.T + b )
__global__ void k_neuron(const float* __restrict__ Spart, float* __restrict__ P,
                         const float* __restrict__ W, const float* __restrict__ b,
                         int col_start)
{
    int gid = blockIdx.x * blockDim.x + threadIdx.x;
    int nl = gid >> 3, j = gid & 7;
    int col = col_start + nl;
    float S[8];
#pragma unroll
    for (int d = 0; d < 8; ++d) {
        float a = 0.f;
#pragma unroll
        for (int rb = 0; rb < 8; ++rb) a += Spart[rb * 8192 + col * 8 + d];
        S[d] = a;
    }
    float z = b[j];
#pragma unroll
    for (int d = 0; d < 8; ++d) z += S[d] * W[j * 8 + d];
    P[col * 8 + j] = tanhf(z);
}

__global__ void k_argmax(const float* __restrict__ P, float* __restrict__ out)
{
    __shared__ float v[64];
    int t = threadIdx.x;
    if (t < 64) v[t] = P[(960 + t) * 8];  // dim 0 of output neurons
    __syncthreads();
    if (t == 0) {
        int best = 0; float bv = v[0];
        for (int j = 1; j < 64; ++j)
            if (v[j] > bv) { bv = v[j]; best = j; }   // strict > = first-index tie-break
        out[0] = (float)best;
    }
}

extern "C" void kernel_launch(void* const* d_in, const int* in_sizes, int n_in,
                              void* d_out, int out_size, void* d_ws, size_t ws_size,
                              hipStream_t stream)
{
    const float* obs      = (const float*)d_in[0];
    const float* reward   = (const float*)d_in[1];
    const int*   A        = (const int*)d_in[2];
    const float* hidden0  = (const float*)d_in[3];
    const float* post0    = (const float*)d_in[4];
    const float* lr       = (const float*)d_in[5];
    const float* fc_in_w  = (const float*)d_in[6];
    const float* fc_in_b  = (const float*)d_in[7];
    const float* fc_hid_w = (const float*)d_in[8];
    const float* fc_hid_b = (const float*)d_in[9];
    const float* fc_out_w = (const float*)d_in[10];
    const float* fc_out_b = (const float*)d_in[11];
    const float* gin_wih  = (const float*)d_in[12];
    const float* gin_whh  = (const float*)d_in[13];
    const float* gin_bih  = (const float*)d_in[14];
    const float* gin_bhh  = (const float*)d_in[15];
    const float* ghid_wih = (const float*)d_in[16];
    const float* ghid_whh = (const float*)d_in[17];
    const float* ghid_bih = (const float*)d_in[18];
    const float* ghid_bhh = (const float*)d_in[19];
    const float* gout_wih = (const float*)d_in[20];
    const float* gout_whh = (const float*)d_in[21];
    const float* gout_bih = (const float*)d_in[22];
    const float* gout_bhh = (const float*)d_in[23];

    float* ws    = (float*)d_ws;
    float* PH    = ws;
    float* Uin   = ws + 7340032;
    float* Utop  = Uin + 524288;
    float* Urt   = Utop + 524288;
    float* Uout  = Urt + 458752;
    float* P     = Uout + 524288;
    float* Spart = P + 8192;

    k_init<<<2048, 256, 0, stream>>>((float4*)PH, P, post0);
    k_inp<<<1, 512, 0, stream>>>(obs, fc_in_w, fc_in_b, P);

    // ---- tick 1 ----
    k_syn_in<1><<<256, 256, 0, stream>>>(A, hidden0, P, PH, Uin, Utop, Uout,
                                         gin_wih, gin_whh, gin_bih, gin_bhh, reward, lr);
    k_colsum<<<dim3(28, 8), 256, 0, stream>>>(PH, Spart, 64, 8);    // only rows<64 written yet
    k_neuron<<<28, 256, 0, stream>>>(Spart, P, fc_hid_w, fc_hid_b, 64);
    k_syn_hid1<<<3584, 256, 0, stream>>>(A, hidden0, P, PH, Utop, Urt,
                                         ghid_wih, ghid_whh, ghid_bih, ghid_bhh, reward, lr);
    k_colsum<<<dim3(2, 8), 256, 0, stream>>>(PH, Spart, 960, 112);
    k_neuron<<<2, 256, 0, stream>>>(Spart, P, fc_out_w, fc_out_b, 960);
    k_syn_out<<<256, 256, 0, stream>>>(A, hidden0, P, PH, Uout,
                                       gout_wih, gout_whh, gout_bih, gout_bhh, reward, lr);

    // ---- tick 2 (input-neuron update identical to tick1 -> skipped; out-syn dead) ----
    k_syn_in<2><<<256, 256, 0, stream>>>(A, hidden0, P, PH, Uin, Utop, Uout,
                                         gin_wih, gin_whh, gin_bih, gin_bhh, reward, lr);
    k_colsum<<<dim3(28, 8), 256, 0, stream>>>(PH, Spart, 64, 112);
    k_neuron<<<28, 256, 0, stream>>>(Spart, P, fc_hid_w, fc_hid_b, 64);
    k_syn_hid2<<<224, 256, 0, stream>>>(A, hidden0, P, PH, Urt,
                                        ghid_wih, ghid_whh, ghid_bih, ghid_bhh, reward, lr);
    k_colsum<<<dim3(2, 8), 256, 0, stream>>>(PH, Spart, 960, 112);
    k_neuron<<<2, 256, 0, stream>>>(Spart, P, fc_out_w, fc_out_b, 960);

    k_argmax<<<1, 64, 0, stream>>>(P, (float*)d_out);
}

// Round 3
// 510.445 us; speedup vs baseline: 2.8394x; 1.0571x over previous
//
#include <hip/hip_runtime.h>
#include <hip/hip_bf16.h>

#define NN 1024
#define DD 8

typedef float f32x8 __attribute__((ext_vector_type(8)));

// ---------------- workspace layout (floats) ----------------
// PH    : [896][1024][8]   offset 0         count 7340032   (zero-init per call)
// Uin   : [64][1024][8]    7340032          524288
// Utop  : [64][1024][8]    7864320          524288          (tick1 hidden upd, rows<64)
// Uright: [896][64][8]     8388608          458752          (tick1 hidden upd, cols>=960)
// Uout  : [64][1024][8]    8847360          524288
// P     : [1024][8]        9371648          8192
// Spart : [8][1024][8]     9379840          65536

__device__ __forceinline__ float gate_x(const float* __restrict__ sW, int j,
                                        f32x8 pre, f32x8 post, float reward)
{
    const float* w = sW + j * 17;            // Wih row j (17 wide)
    float a = sW[600 + j] + w[16] * reward;  // Bih[j] + reward term
#pragma unroll
    for (int d = 0; d < 8; ++d) a += w[d] * pre[d];
#pragma unroll
    for (int d = 0; d < 8; ++d) a += w[8 + d] * post[d];
    return a;
}

__device__ __forceinline__ float gate_h(const float* __restrict__ sW, int j, f32x8 h)
{
    const float* wh = sW + 408 + j * 8;      // Whh row j
    float b = sW[624 + j];                   // Bhh[j]
#pragma unroll
    for (int d = 0; d < 8; ++d) b += wh[d] * h[d];
    return b;
}

// All state in ext_vector registers; every element access is compile-time-constant
// after full unroll -> no scratch (SROA-proof by construction).
__device__ __forceinline__ f32x8 gru_upd(const float* __restrict__ sW,
                                         f32x8 pre, f32x8 post, f32x8 h,
                                         float reward, float lr)
{
    f32x8 upd;
#pragma unroll
    for (int d = 0; d < 8; ++d) {
        float xr = gate_x(sW, d,      pre, post, reward);
        float hr = gate_h(sW, d,      h);
        float xz = gate_x(sW, 8 + d,  pre, post, reward);
        float hz = gate_h(sW, 8 + d,  h);
        float xn = gate_x(sW, 16 + d, pre, post, reward);
        float hn = gate_h(sW, 16 + d, h);
        float r  = 1.f / (1.f + expf(-(xr + hr)));
        float z  = 1.f / (1.f + expf(-(xz + hz)));
        float nn = tanhf(xn + r * hn);
        float g  = (1.f - z) * nn + z * h[d];
        upd[d] = h[d] + g * lr;
    }
    return upd;
}

#define STAGE_W()                                                                      \
    __shared__ float sW[648];                                                          \
    for (int i = threadIdx.x; i < 648; i += blockDim.x)                                \
        sW[i] = (i < 408) ? Wih[i] : (i < 600) ? Whh[i - 408]                          \
                          : (i < 624) ? Bih[i - 600] : Bhh[i - 624];                   \
    __syncthreads();

__device__ __forceinline__ f32x8 ld8(const float* __restrict__ p)
{
    return *(const f32x8*)p;
}
__device__ __forceinline__ void st8(float* __restrict__ p, f32x8 v)
{
    *(f32x8*)p = v;
}

__global__ void k_init(float4* __restrict__ PH4, float* __restrict__ P,
                       const float* __restrict__ post0)
{
    const int nph4 = 7340032 / 4;
    int stride = gridDim.x * blockDim.x;
    int gid = blockIdx.x * blockDim.x + threadIdx.x;
    float4 z; z.x = z.y = z.z = z.w = 0.f;
    for (int i = gid; i < nph4; i += stride) PH4[i] = z;
    if (gid < 8192) P[gid] = post0[gid];
}

__global__ void k_inp(const float* __restrict__ obs, const float* __restrict__ W,
                      const float* __restrict__ b, float* __restrict__ P)
{
    int t = threadIdx.x;           // 512 = 64 neurons x 8 dims
    int i = t >> 3, j = t & 7;
    float rs = 0.f;
#pragma unroll
    for (int d = 0; d < 8; ++d) rs += W[j * 8 + d];
    P[i * 8 + j] = tanhf(obs[i] * rs + b[j]);
}

// input-layer synapses: rows r in [0,64), all cols, mask A[r][n]
template <int TICK>
__global__ void k_syn_in(const int* __restrict__ A, const float* __restrict__ hidden0,
                         const float* __restrict__ P, float* __restrict__ PH,
                         float* __restrict__ Uin, const float* __restrict__ Utop,
                         const float* __restrict__ Uout,
                         const float* __restrict__ Wih, const float* __restrict__ Whh,
                         const float* __restrict__ Bih, const float* __restrict__ Bhh,
                         const float* __restrict__ reward, const float* __restrict__ lr)
{
    STAGE_W();
    int gid = blockIdx.x * blockDim.x + threadIdx.x;
    int r = gid >> 10, n = gid & 1023;
    if (!A[r * NN + n]) return;
    int e = (r * NN + n) * 8;
    f32x8 pre  = ld8(P + r * 8);
    f32x8 post = ld8(P + n * 8);
    f32x8 h;
    if (TICK == 1) {
        h = ld8(hidden0 + e);
    } else {
        const float* src;
        if (A[(960 + r) * NN + n])      src = Uout + e;
        else if (A[(64 + r) * NN + n])  src = Utop + e;
        else                            src = Uin + e;
        h = ld8(src);
    }
    f32x8 upd = gru_upd(sW, pre, post, h, reward[0], lr[0]);
    st8(PH + e, upd * pre);
    if (TICK == 1) st8(Uin + e, upd);
}

// hidden-layer synapses tick1: l in [0,896), all cols, mask A[64+l][n]
__global__ void k_syn_hid1(const int* __restrict__ A, const float* __restrict__ hidden0,
                           const float* __restrict__ P, float* __restrict__ PH,
                           float* __restrict__ Utop, float* __restrict__ Uright,
                           const float* __restrict__ Wih, const float* __restrict__ Whh,
                           const float* __restrict__ Bih, const float* __restrict__ Bhh,
                           const float* __restrict__ reward, const float* __restrict__ lr)
{
    STAGE_W();
    int gid = blockIdx.x * blockDim.x + threadIdx.x;
    int l = gid >> 10, n = gid & 1023;
    if (!A[(64 + l) * NN + n]) return;
    f32x8 pre  = ld8(P + (64 + l) * 8);
    f32x8 post = ld8(P + n * 8);
    int eh = ((64 + l) * NN + n) * 8;
    f32x8 h = ld8(hidden0 + eh);
    f32x8 upd = gru_upd(sW, pre, post, h, reward[0], lr[0]);
    int e = (l * NN + n) * 8;
    st8(PH + e, upd * pre);
    if (l < 64) st8(Utop + e, upd);
    if (n >= 960) st8(Uright + (l * 64 + (n - 960)) * 8, upd);
}

// hidden-layer synapses tick2: only cols n in [960,1024) matter afterwards
__global__ void k_syn_hid2(const int* __restrict__ A, const float* __restrict__ hidden0,
                           const float* __restrict__ P, float* __restrict__ PH,
                           const float* __restrict__ Uright,
                           const float* __restrict__ Wih, const float* __restrict__ Whh,
                           const float* __restrict__ Bih, const float* __restrict__ Bhh,
                           const float* __restrict__ reward, const float* __restrict__ lr)
{
    STAGE_W();
    int gid = blockIdx.x * blockDim.x + threadIdx.x;
    int l = gid >> 6, nn = gid & 63, n = 960 + nn;
    if (!A[(64 + l) * NN + n]) return;
    f32x8 pre  = ld8(P + (64 + l) * 8);
    f32x8 post = ld8(P + n * 8);
    // h = H[64+l][n] after tick1
    const float* hp;
    if (l < 832 && A[(128 + l) * NN + n]) hp = Uright + ((64 + l) * 64 + nn) * 8;
    else                                  hp = hidden0 + ((64 + l) * NN + n) * 8;
    f32x8 h = ld8(hp);
    f32x8 upd = gru_upd(sW, pre, post, h, reward[0], lr[0]);
    st8(PH + (l * NN + n) * 8, upd * pre);
}

// output-layer synapses (tick1 only): rows 960+l, mask A[960+l][n]
__global__ void k_syn_out(const int* __restrict__ A, const float* __restrict__ hidden0,
                          const float* __restrict__ P, float* __restrict__ PH,
                          float* __restrict__ Uout,
                          const float* __restrict__ Wih, const float* __restrict__ Whh,
                          const float* __restrict__ Bih, const float* __restrict__ Bhh,
                          const float* __restrict__ reward, const float* __restrict__ lr)
{
    STAGE_W();
    int gid = blockIdx.x * blockDim.x + threadIdx.x;
    int l = gid >> 10, n = gid & 1023;
    if (!A[(960 + l) * NN + n]) return;
    f32x8 pre  = ld8(P + (960 + l) * 8);
    f32x8 post = ld8(P + n * 8);
    int eh = ((960 + l) * NN + n) * 8;
    f32x8 h = ld8(hidden0 + eh);
    f32x8 upd = gru_upd(sW, pre, post, h, reward[0], lr[0]);
    int e = (l * NN + n) * 8;
    st8(PH + e, upd * pre);
    st8(Uout + e, upd);
}

// partial column sums over PH: grid (ncolgroups, 8 rowblocks), 256 thr = 32 cols x 8 dims
__global__ void k_colsum(const float* __restrict__ PH, float* __restrict__ Spart,
                         int col_start, int rows_per_block)
{
    int base = (col_start + blockIdx.x * 32) * 8 + threadIdx.x;
    int r0 = blockIdx.y * rows_per_block;
    float acc = 0.f;
    for (int k = 0; k < rows_per_block; ++k)
        acc += PH[(r0 + k) * 8192 + base];
    Spart[blockIdx.y * 8192 + base] = acc;
}

// neuron update: P[col] = tanh( (sum_rb Spart) @ W.T + b )
__global__ void k_neuron(const float* __restrict__ Spart, float* __restrict__ P,
                         const float* __restrict__ W, const float* __restrict__ b,
                         int col_start)
{
    int gid = blockIdx.x * blockDim.x + threadIdx.x;
    int nl = gid >> 3, j = gid & 7;
    int col = col_start + nl;
    float z = b[j];
#pragma unroll
    for (int d = 0; d < 8; ++d) {
        float a = 0.f;
#pragma unroll
        for (int rb = 0; rb < 8; ++rb) a += Spart[rb * 8192 + col * 8 + d];
        z += a * W[j * 8 + d];
    }
    P[col * 8 + j] = tanhf(z);
}

__global__ void k_argmax(const float* __restrict__ P, float* __restrict__ out)
{
    __shared__ float v[64];
    int t = threadIdx.x;
    if (t < 64) v[t] = P[(960 + t) * 8];  // dim 0 of output neurons
    __syncthreads();
    if (t == 0) {
        int best = 0; float bv = v[0];
        for (int j = 1; j < 64; ++j)
            if (v[j] > bv) { bv = v[j]; best = j; }   // strict > = first-index tie-break
        out[0] = (float)best;
    }
}

extern "C" void kernel_launch(void* const* d_in, const int* in_sizes, int n_in,
                              void* d_out, int out_size, void* d_ws, size_t ws_size,
                              hipStream_t stream)
{
    const float* obs      = (const float*)d_in[0];
    const float* reward   = (const float*)d_in[1];
    const int*   A        = (const int*)d_in[2];
    const float* hidden0  = (const float*)d_in[3];
    const float* post0    = (const float*)d_in[4];
    const float* lr       = (const float*)d_in[5];
    const float* fc_in_w  = (const float*)d_in[6];
    const float* fc_in_b  = (const float*)d_in[7];
    const float* fc_hid_w = (const float*)d_in[8];
    const float* fc_hid_b = (const float*)d_in[9];
    const float* fc_out_w = (const float*)d_in[10];
    const float* fc_out_b = (const float*)d_in[11];
    const float* gin_wih  = (const float*)d_in[12];
    const float* gin_whh  = (const float*)d_in[13];
    const float* gin_bih  = (const float*)d_in[14];
    const float* gin_bhh  = (const float*)d_in[15];
    const float* ghid_wih = (const float*)d_in[16];
    const float* ghid_whh = (const float*)d_in[17];
    const float* ghid_bih = (const float*)d_in[18];
    const float* ghid_bhh = (const float*)d_in[19];
    const float* gout_wih = (const float*)d_in[20];
    const float* gout_whh = (const float*)d_in[21];
    const float* gout_bih = (const float*)d_in[22];
    const float* gout_bhh = (const float*)d_in[23];

    float* ws    = (float*)d_ws;
    float* PH    = ws;
    float* Uin   = ws + 7340032;
    float* Utop  = Uin + 524288;
    float* Urt   = Utop + 524288;
    float* Uout  = Urt + 458752;
    float* P     = Uout + 524288;
    float* Spart = P + 8192;

    k_init<<<2048, 256, 0, stream>>>((float4*)PH, P, post0);
    k_inp<<<1, 512, 0, stream>>>(obs, fc_in_w, fc_in_b, P);

    // ---- tick 1 ----
    k_syn_in<1><<<256, 256, 0, stream>>>(A, hidden0, P, PH, Uin, Utop, Uout,
                                         gin_wih, gin_whh, gin_bih, gin_bhh, reward, lr);
    k_colsum<<<dim3(28, 8), 256, 0, stream>>>(PH, Spart, 64, 8);    // only rows<64 written yet
    k_neuron<<<28, 256, 0, stream>>>(Spart, P, fc_hid_w, fc_hid_b, 64);
    k_syn_hid1<<<3584, 256, 0, stream>>>(A, hidden0, P, PH, Utop, Urt,
                                         ghid_wih, ghid_whh, ghid_bih, ghid_bhh, reward, lr);
    k_colsum<<<dim3(2, 8), 256, 0, stream>>>(PH, Spart, 960, 112);
    k_neuron<<<2, 256, 0, stream>>>(Spart, P, fc_out_w, fc_out_b, 960);
    k_syn_out<<<256, 256, 0, stream>>>(A, hidden0, P, PH, Uout,
                                       gout_wih, gout_whh, gout_bih, gout_bhh, reward, lr);

    // ---- tick 2 (input-neuron update identical to tick1 -> skipped; out-syn dead) ----
    k_syn_in<2><<<256, 256, 0, stream>>>(A, hidden0, P, PH, Uin, Utop, Uout,
                                         gin_wih, gin_whh, gin_bih, gin_bhh, reward, lr);
    k_colsum<<<dim3(28, 8), 256, 0, stream>>>(PH, Spart, 64, 112);
    k_neuron<<<28, 256, 0, stream>>>(Spart, P, fc_hid_w, fc_hid_b, 64);
    k_syn_hid2<<<224, 256, 0, stream>>>(A, hidden0, P, PH, Urt,
                                        ghid_wih, ghid_whh, ghid_bih, ghid_bhh, reward, lr);
    k_colsum<<<dim3(2, 8), 256, 0, stream>>>(PH, Spart, 960, 112);
    k_neuron<<<2, 256, 0, stream>>>(Spart, P, fc_out_w, fc_out_b, 960);

    k_argmax<<<1, 64, 0, stream>>>(P, (float*)d_out);
}

// Round 4
// 265.180 us; speedup vs baseline: 5.4656x; 1.9249x over previous
//
#include <hip/hip_runtime.h>
#include <hip/hip_bf16.h>

#define NN 1024
#define DD 8

typedef float f32x8 __attribute__((ext_vector_type(8)));

// ---------------- workspace layout (floats) ----------------
// PH    : [896][1024][8]   offset 0         count 7340032   (zero-init per call)
// Uin   : [64][1024][8]    7340032          524288
// Utop  : [64][1024][8]    7864320          524288          (tick1 hidden upd, rows<64)
// Uright: [896][64][8]     8388608          458752          (tick1 hidden upd, cols>=960)
// Uout  : [64][1024][8]    8847360          524288
// P     : [1024][8]        9371648          8192
// Spart : [8][1024][8]     9379840          65536

__device__ __forceinline__ float gate_x(const float* __restrict__ sW, int j,
                                        f32x8 pre, f32x8 post, float reward)
{
    const float* w = sW + j * 17;            // Wih row j (17 wide)
    float a = sW[600 + j] + w[16] * reward;  // Bih[j] + reward term
#pragma unroll
    for (int d = 0; d < 8; ++d) a += w[d] * pre[d];
#pragma unroll
    for (int d = 0; d < 8; ++d) a += w[8 + d] * post[d];
    return a;
}

__device__ __forceinline__ float gate_h(const float* __restrict__ sW, int j, f32x8 h)
{
    const float* wh = sW + 408 + j * 8;      // Whh row j
    float b = sW[624 + j];                   // Bhh[j]
#pragma unroll
    for (int d = 0; d < 8; ++d) b += wh[d] * h[d];
    return b;
}

__device__ __forceinline__ f32x8 gru_upd(const float* __restrict__ sW,
                                         f32x8 pre, f32x8 post, f32x8 h,
                                         float reward, float lr)
{
    f32x8 upd;
#pragma unroll
    for (int d = 0; d < 8; ++d) {
        float xr = gate_x(sW, d,      pre, post, reward);
        float hr = gate_h(sW, d,      h);
        float xz = gate_x(sW, 8 + d,  pre, post, reward);
        float hz = gate_h(sW, 8 + d,  h);
        float xn = gate_x(sW, 16 + d, pre, post, reward);
        float hn = gate_h(sW, 16 + d, h);
        float r  = 1.f / (1.f + expf(-(xr + hr)));
        float z  = 1.f / (1.f + expf(-(xz + hz)));
        float nn = tanhf(xn + r * hn);
        float g  = (1.f - z) * nn + z * h[d];
        upd[d] = h[d] + g * lr;
    }
    return upd;
}

#define STAGE_W()                                                                      \
    __shared__ float sW[648];                                                          \
    for (int i = threadIdx.x; i < 648; i += blockDim.x)                                \
        sW[i] = (i < 408) ? Wih[i] : (i < 600) ? Whh[i - 408]                          \
                          : (i < 624) ? Bih[i - 600] : Bhh[i - 624];                   \
    __syncthreads();

__device__ __forceinline__ f32x8 ld8(const float* __restrict__ p)
{
    return *(const f32x8*)p;
}
__device__ __forceinline__ void st8(float* __restrict__ p, f32x8 v)
{
    *(f32x8*)p = v;
}

__global__ void __launch_bounds__(256, 2)
k_init(float4* __restrict__ PH4, float* __restrict__ P, const float* __restrict__ post0)
{
    const int nph4 = 7340032 / 4;
    int stride = gridDim.x * blockDim.x;
    int gid = blockIdx.x * blockDim.x + threadIdx.x;
    float4 z; z.x = z.y = z.z = z.w = 0.f;
    for (int i = gid; i < nph4; i += stride) PH4[i] = z;
    if (gid < 8192) P[gid] = post0[gid];
}

__global__ void __launch_bounds__(512, 2)
k_inp(const float* __restrict__ obs, const float* __restrict__ W,
      const float* __restrict__ b, float* __restrict__ P)
{
    int t = threadIdx.x;           // 512 = 64 neurons x 8 dims
    int i = t >> 3, j = t & 7;
    float rs = 0.f;
#pragma unroll
    for (int d = 0; d < 8; ++d) rs += W[j * 8 + d];
    P[i * 8 + j] = tanhf(obs[i] * rs + b[j]);
}

// input-layer synapses: rows r in [0,64), cols 256*(bid&3).., mask A[r][n]
template <int TICK>
__global__ void __launch_bounds__(256, 2)
k_syn_in(const int* __restrict__ A, const float* __restrict__ hidden0,
         const float* __restrict__ P, float* __restrict__ PH,
         float* __restrict__ Uin, const float* __restrict__ Utop,
         const float* __restrict__ Uout,
         const float* __restrict__ Wih, const float* __restrict__ Whh,
         const float* __restrict__ Bih, const float* __restrict__ Bhh,
         const float* __restrict__ reward, const float* __restrict__ lr)
{
    STAGE_W();
    int r = blockIdx.x >> 2;                                   // scalar (uniform)
    int n = ((blockIdx.x & 3) << 8) | threadIdx.x;
    if (!A[r * NN + n]) return;
    int e = (r * NN + n) * 8;
    f32x8 pre  = ld8(P + r * 8);
    f32x8 post = ld8(P + n * 8);
    f32x8 h;
    if (TICK == 1) {
        h = ld8(hidden0 + e);
    } else {
        const float* src;
        if (A[(960 + r) * NN + n])      src = Uout + e;
        else if (A[(64 + r) * NN + n])  src = Utop + e;
        else                            src = Uin + e;
        h = ld8(src);
    }
    f32x8 upd = gru_upd(sW, pre, post, h, reward[0], lr[0]);
    st8(PH + e, upd * pre);
    if (TICK == 1) st8(Uin + e, upd);
}

// hidden-layer synapses tick1: l in [0,896), mask A[64+l][n]
__global__ void __launch_bounds__(256, 2)
k_syn_hid1(const int* __restrict__ A, const float* __restrict__ hidden0,
           const float* __restrict__ P, float* __restrict__ PH,
           float* __restrict__ Utop, float* __restrict__ Uright,
           const float* __restrict__ Wih, const float* __restrict__ Whh,
           const float* __restrict__ Bih, const float* __restrict__ Bhh,
           const float* __restrict__ reward, const float* __restrict__ lr)
{
    STAGE_W();
    int l = blockIdx.x >> 2;                                   // scalar (uniform)
    int n = ((blockIdx.x & 3) << 8) | threadIdx.x;
    if (!A[(64 + l) * NN + n]) return;
    f32x8 pre  = ld8(P + (64 + l) * 8);
    f32x8 post = ld8(P + n * 8);
    int eh = ((64 + l) * NN + n) * 8;
    f32x8 h = ld8(hidden0 + eh);
    f32x8 upd = gru_upd(sW, pre, post, h, reward[0], lr[0]);
    int e = (l * NN + n) * 8;
    st8(PH + e, upd * pre);
    if (l < 64) st8(Utop + e, upd);
    if (n >= 960) st8(Uright + (l * 64 + (n - 960)) * 8, upd);
}

// hidden-layer synapses tick2: only cols n in [960,1024) matter afterwards
__global__ void __launch_bounds__(256, 2)
k_syn_hid2(const int* __restrict__ A, const float* __restrict__ hidden0,
           const float* __restrict__ P, float* __restrict__ PH,
           const float* __restrict__ Uright,
           const float* __restrict__ Wih, const float* __restrict__ Whh,
           const float* __restrict__ Bih, const float* __restrict__ Bhh,
           const float* __restrict__ reward, const float* __restrict__ lr)
{
    STAGE_W();
    int gid = blockIdx.x * blockDim.x + threadIdx.x;
    int l = gid >> 6, nn = gid & 63, n = 960 + nn;
    if (!A[(64 + l) * NN + n]) return;
    f32x8 pre  = ld8(P + (64 + l) * 8);
    f32x8 post = ld8(P + n * 8);
    const float* hp;
    if (l < 832 && A[(128 + l) * NN + n]) hp = Uright + ((64 + l) * 64 + nn) * 8;
    else                                  hp = hidden0 + ((64 + l) * NN + n) * 8;
    f32x8 h = ld8(hp);
    f32x8 upd = gru_upd(sW, pre, post, h, reward[0], lr[0]);
    st8(PH + (l * NN + n) * 8, upd * pre);
}

// output-layer synapses (tick1 only): rows 960+l, mask A[960+l][n]
__global__ void __launch_bounds__(256, 2)
k_syn_out(const int* __restrict__ A, const float* __restrict__ hidden0,
          const float* __restrict__ P, float* __restrict__ PH,
          float* __restrict__ Uout,
          const float* __restrict__ Wih, const float* __restrict__ Whh,
          const float* __restrict__ Bih, const float* __restrict__ Bhh,
          const float* __restrict__ reward, const float* __restrict__ lr)
{
    STAGE_W();
    int l = blockIdx.x >> 2;                                   // scalar (uniform)
    int n = ((blockIdx.x & 3) << 8) | threadIdx.x;
    if (!A[(960 + l) * NN + n]) return;
    f32x8 pre  = ld8(P + (960 + l) * 8);
    f32x8 post = ld8(P + n * 8);
    int eh = ((960 + l) * NN + n) * 8;
    f32x8 h = ld8(hidden0 + eh);
    f32x8 upd = gru_upd(sW, pre, post, h, reward[0], lr[0]);
    int e = (l * NN + n) * 8;
    st8(PH + e, upd * pre);
    st8(Uout + e, upd);
}

// partial column sums over PH: grid (ncolgroups, 8 rowblocks), 256 thr = 32 cols x 8 dims
__global__ void __launch_bounds__(256, 2)
k_colsum(const float* __restrict__ PH, float* __restrict__ Spart,
         int col_start, int rows_per_block)
{
    int base = (col_start + blockIdx.x * 32) * 8 + threadIdx.x;
    int r0 = blockIdx.y * rows_per_block;
    float acc = 0.f;
    for (int k = 0; k < rows_per_block; ++k)
        acc += PH[(r0 + k) * 8192 + base];
    Spart[blockIdx.y * 8192 + base] = acc;
}

// neuron update: P[col] = tanh( (sum_rb Spart) @ W.T + b )
__global__ void __launch_bounds__(256, 2)
k_neuron(const float* __restrict__ Spart, float* __restrict__ P,
         const float* __restrict__ W, const float* __restrict__ b,
         int col_start)
{
    int gid = blockIdx.x * blockDim.x + threadIdx.x;
    int nl = gid >> 3, j = gid & 7;
    int col = col_start + nl;
    float z = b[j];
#pragma unroll
    for (int d = 0; d < 8; ++d) {
        float a = 0.f;
#pragma unroll
        for (int rb = 0; rb < 8; ++rb) a += Spart[rb * 8192 + col * 8 + d];
        z += a * W[j * 8 + d];
    }
    P[col * 8 + j] = tanhf(z);
}

__global__ void __launch_bounds__(64, 2)
k_argmax(const float* __restrict__ P, float* __restrict__ out)
{
    __shared__ float v[64];
    int t = threadIdx.x;
    if (t < 64) v[t] = P[(960 + t) * 8];  // dim 0 of output neurons
    __syncthreads();
    if (t == 0) {
        int best = 0; float bv = v[0];
        for (int j = 1; j < 64; ++j)
            if (v[j] > bv) { bv = v[j]; best = j; }   // strict > = first-index tie-break
        out[0] = (float)best;
    }
}

extern "C" void kernel_launch(void* const* d_in, const int* in_sizes, int n_in,
                              void* d_out, int out_size, void* d_ws, size_t ws_size,
                              hipStream_t stream)
{
    const float* obs      = (const float*)d_in[0];
    const float* reward   = (const float*)d_in[1];
    const int*   A        = (const int*)d_in[2];
    const float* hidden0  = (const float*)d_in[3];
    const float* post0    = (const float*)d_in[4];
    const float* lr       = (const float*)d_in[5];
    const float* fc_in_w  = (const float*)d_in[6];
    const float* fc_in_b  = (const float*)d_in[7];
    const float* fc_hid_w = (const float*)d_in[8];
    const float* fc_hid_b = (const float*)d_in[9];
    const float* fc_out_w = (const float*)d_in[10];
    const float* fc_out_b = (const float*)d_in[11];
    const float* gin_wih  = (const float*)d_in[12];
    const float* gin_whh  = (const float*)d_in[13];
    const float* gin_bih  = (const float*)d_in[14];
    const float* gin_bhh  = (const float*)d_in[15];
    const float* ghid_wih = (const float*)d_in[16];
    const float* ghid_whh = (const float*)d_in[17];
    const float* ghid_bih = (const float*)d_in[18];
    const float* ghid_bhh = (const float*)d_in[19];
    const float* gout_wih = (const float*)d_in[20];
    const float* gout_whh = (const float*)d_in[21];
    const float* gout_bih = (const float*)d_in[22];
    const float* gout_bhh = (const float*)d_in[23];

    float* ws    = (float*)d_ws;
    float* PH    = ws;
    float* Uin   = ws + 7340032;
    float* Utop  = Uin + 524288;
    float* Urt   = Utop + 524288;
    float* Uout  = Urt + 458752;
    float* P     = Uout + 524288;
    float* Spart = P + 8192;

    k_init<<<2048, 256, 0, stream>>>((float4*)PH, P, post0);
    k_inp<<<1, 512, 0, stream>>>(obs, fc_in_w, fc_in_b, P);

    // ---- tick 1 ----
    k_syn_in<1><<<256, 256, 0, stream>>>(A, hidden0, P, PH, Uin, Utop, Uout,
                                         gin_wih, gin_whh, gin_bih, gin_bhh, reward, lr);
    k_colsum<<<dim3(28, 8), 256, 0, stream>>>(PH, Spart, 64, 8);    // only rows<64 written yet
    k_neuron<<<28, 256, 0, stream>>>(Spart, P, fc_hid_w, fc_hid_b, 64);
    k_syn_hid1<<<3584, 256, 0, stream>>>(A, hidden0, P, PH, Utop, Urt,
                                         ghid_wih, ghid_whh, ghid_bih, ghid_bhh, reward, lr);
    k_colsum<<<dim3(2, 8), 256, 0, stream>>>(PH, Spart, 960, 112);
    k_neuron<<<2, 256, 0, stream>>>(Spart, P, fc_out_w, fc_out_b, 960);
    k_syn_out<<<256, 256, 0, stream>>>(A, hidden0, P, PH, Uout,
                                       gout_wih, gout_whh, gout_bih, gout_bhh, reward, lr);

    // ---- tick 2 (input-neuron update identical to tick1 -> skipped; out-syn dead) ----
    k_syn_in<2><<<256, 256, 0, stream>>>(A, hidden0, P, PH, Uin, Utop, Uout,
                                         gin_wih, gin_whh, gin_bih, gin_bhh, reward, lr);
    k_colsum<<<dim3(28, 8), 256, 0, stream>>>(PH, Spart, 64, 112);
    k_neuron<<<28, 256, 0, stream>>>(Spart, P, fc_hid_w, fc_hid_b, 64);
    k_syn_hid2<<<224, 256, 0, stream>>>(A, hidden0, P, PH, Urt,
                                        ghid_wih, ghid_whh, ghid_bih, ghid_bhh, reward, lr);
    k_colsum<<<dim3(2, 8), 256, 0, stream>>>(PH, Spart, 960, 112);
    k_neuron<<<2, 256, 0, stream>>>(Spart, P, fc_out_w, fc_out_b, 960);

    k_argmax<<<1, 64, 0, stream>>>(P, (float*)d_out);
}

// Round 5
// 169.528 us; speedup vs baseline: 8.5494x; 1.5642x over previous
//
#include <hip/hip_runtime.h>
#include <hip/hip_bf16.h>

#define NN 1024
#define DD 8

typedef float f32x8 __attribute__((ext_vector_type(8)));

// ---------------- workspace layout (floats) ----------------
// PH    : [896][1024][8]   offset 0         count 7340032   (NO zero-init: writers cover)
// Uin   : [64][1024][8]    7340032          524288
// Utop  : [64][1024][8]    7864320          524288          (tick1 hidden upd, rows<64)
// Uright: [896][64][8]     8388608          458752          (tick1 hidden upd, cols>=960)
// Uout  : [64][1024][8]    8847360          524288
// P     : [1024][8]        9371648          8192
// Spart : [8][1024][8]     9379840          65536

__device__ __forceinline__ float sigmoid_f(float x)
{
    return __fdividef(1.f, 1.f + __expf(-x));
}
__device__ __forceinline__ float tanh_f(float x)
{
    float ax = fabsf(x);
    float e  = __expf(-2.f * ax);                  // in (0,1], no overflow
    float t  = __fdividef(1.f - e, 1.f + e);
    return copysignf(t, x);
}

__device__ __forceinline__ f32x8 ld8(const float* __restrict__ p) { return *(const f32x8*)p; }
__device__ __forceinline__ void st8(float* __restrict__ p, f32x8 v) { *(f32x8*)p = v; }

// Per-edge GRU with row-uniform gx part prehoisted into sGX[24].
// gx_j = sGX[j] + sWP[j][:]·post ; gh_j = sBhh[j] + sWH[j][:]·h
__device__ __forceinline__ f32x8 gru_fast(const float (*__restrict__ sWP)[8],
                                          const float (*__restrict__ sWH)[8],
                                          const float* __restrict__ sGX,
                                          const float* __restrict__ sBhh,
                                          f32x8 post, f32x8 h, float lr)
{
    f32x8 upd;
#pragma unroll
    for (int d = 0; d < 8; ++d) {
        float xr = sGX[d],      hr = sBhh[d];
        float xz = sGX[8 + d],  hz = sBhh[8 + d];
        float xn = sGX[16 + d], hn = sBhh[16 + d];
#pragma unroll
        for (int k = 0; k < 8; ++k) {
            xr = fmaf(sWP[d][k],      post[k], xr);
            hr = fmaf(sWH[d][k],      h[k],    hr);
            xz = fmaf(sWP[8 + d][k],  post[k], xz);
            hz = fmaf(sWH[8 + d][k],  h[k],    hz);
            xn = fmaf(sWP[16 + d][k], post[k], xn);
            hn = fmaf(sWH[16 + d][k], h[k],    hn);
        }
        float r  = sigmoid_f(xr + hr);
        float z  = sigmoid_f(xz + hz);
        float nv = tanh_f(fmaf(r, hn, xn));
        float g  = (1.f - z) * nv + z * h[d];
        upd[d] = fmaf(g, lr, h[d]);
    }
    return upd;
}

// Stage weights + row-uniform gx part for single-row blocks (row known, P ready).
#define STAGE_SYN(ROW)                                                                 \
    __shared__ float sWP[24][8], sWH[24][8];                                           \
    __shared__ float sGX[24], sBhh[24];                                                \
    {                                                                                  \
        int t_ = threadIdx.x;                                                          \
        if (t_ < 192) {                                                                \
            int j = t_ >> 3, k = t_ & 7;                                               \
            sWP[j][k] = Wih[j * 17 + 8 + k];                                           \
            sWH[j][k] = Whh[j * 8 + k];                                                \
        } else if (t_ < 216) {                                                         \
            int j = t_ - 192;                                                          \
            float rp = Bih[j] + Wih[j * 17 + 16] * reward[0];                          \
            const float* pr = P + (ROW) * 8;                                           \
            for (int k = 0; k < 8; ++k) rp += Wih[j * 17 + k] * pr[k];                 \
            sGX[j] = rp;                                                               \
            sBhh[j] = Bhh[j];                                                          \
        }                                                                              \
        __syncthreads();                                                               \
    }

// P prep: rows<64 = input-layer tanh, rows>=64 = post0 copy
__global__ void __launch_bounds__(256)
k_prep(const float* __restrict__ obs, const float* __restrict__ W,
       const float* __restrict__ b, const float* __restrict__ post0,
       float* __restrict__ P)
{
    int gid = blockIdx.x * 256 + threadIdx.x;     // 8192 threads
    if (gid < 512) {
        int i = gid >> 3, j = gid & 7;
        float rs = 0.f;
#pragma unroll
        for (int d = 0; d < 8; ++d) rs += W[j * 8 + d];
        P[gid] = tanhf(obs[i] * rs + b[j]);
    } else {
        P[gid] = post0[gid];
    }
}

// input-layer synapses: row r=bid>>2 in [0,64), 256 cols per block, mask A[r][n]
// TICK1: write zero where inactive (PH base is uninitialized); TICK2: skip-if-inactive.
template <int TICK>
__global__ void __launch_bounds__(256, 4)
k_syn_in(const int* __restrict__ A, const float* __restrict__ hidden0,
         const float* __restrict__ P, float* __restrict__ PH,
         float* __restrict__ Uin, const float* __restrict__ Utop,
         const float* __restrict__ Uout,
         const float* __restrict__ Wih, const float* __restrict__ Whh,
         const float* __restrict__ Bih, const float* __restrict__ Bhh,
         const float* __restrict__ reward, const float* __restrict__ lr)
{
    int r = blockIdx.x >> 2;
    STAGE_SYN(r);
    int n = ((blockIdx.x & 3) << 8) | threadIdx.x;
    int e = (r * NN + n) * 8;
    bool act = A[r * NN + n] != 0;
    if (!act) {
        if (TICK == 1) { f32x8 z{}; st8(PH + e, z); }
        return;
    }
    f32x8 post = ld8(P + n * 8);
    f32x8 h;
    if (TICK == 1) {
        h = ld8(hidden0 + e);
    } else {
        const float* src;
        if (A[(960 + r) * NN + n])      src = Uout + e;
        else if (A[(64 + r) * NN + n])  src = Utop + e;
        else                            src = Uin + e;   // m_in active here by construction
        h = ld8(src);
    }
    f32x8 upd = gru_fast(sWP, sWH, sGX, sBhh, post, h, lr[0]);
    f32x8 pre = ld8(P + r * 8);
    st8(PH + e, upd * pre);
    if (TICK == 1) st8(Uin + e, upd);
}

// hidden-layer synapses tick1: row l=bid>>2 in [0,896), mask A[64+l][n]
// l<64: skip-if-inactive (preserve syn_in values); l>=64: zero-if-inactive.
__global__ void __launch_bounds__(256, 4)
k_syn_hid1(const int* __restrict__ A, const float* __restrict__ hidden0,
           const float* __restrict__ P, float* __restrict__ PH,
           float* __restrict__ Utop, float* __restrict__ Uright,
           const float* __restrict__ Wih, const float* __restrict__ Whh,
           const float* __restrict__ Bih, const float* __restrict__ Bhh,
           const float* __restrict__ reward, const float* __restrict__ lr)
{
    int l = blockIdx.x >> 2;
    STAGE_SYN(64 + l);
    int n = ((blockIdx.x & 3) << 8) | threadIdx.x;
    int e = (l * NN + n) * 8;
    bool act = A[(64 + l) * NN + n] != 0;
    if (!act) {
        if (l >= 64) { f32x8 z{}; st8(PH + e, z); }
        return;
    }
    f32x8 post = ld8(P + n * 8);
    f32x8 h = ld8(hidden0 + ((64 + l) * NN + n) * 8);
    f32x8 upd = gru_fast(sWP, sWH, sGX, sBhh, post, h, lr[0]);
    f32x8 pre = ld8(P + (64 + l) * 8);
    st8(PH + e, upd * pre);
    if (l < 64) st8(Utop + e, upd);
    if (n >= 960) st8(Uright + (l * 64 + (n - 960)) * 8, upd);
}

// hidden-layer synapses tick2: only cols [960,1024) observable; skip-if-inactive.
// 4 rows per block (64 cols each).
__global__ void __launch_bounds__(256, 4)
k_syn_hid2(const int* __restrict__ A, const float* __restrict__ hidden0,
           const float* __restrict__ P, float* __restrict__ PH,
           const float* __restrict__ Uright,
           const float* __restrict__ Wih, const float* __restrict__ Whh,
           const float* __restrict__ Bih, const float* __restrict__ Bhh,
           const float* __restrict__ reward, const float* __restrict__ lr)
{
    __shared__ float sWP[24][8], sWH[24][8], sBhh[24];
    __shared__ float sGX4[4][24];
    int t = threadIdx.x;
    if (t < 192) {
        int j = t >> 3, k = t & 7;
        sWP[j][k] = Wih[j * 17 + 8 + k];
        sWH[j][k] = Whh[j * 8 + k];
    } else if (t < 216) {
        sBhh[t - 192] = Bhh[t - 192];
    }
    if (t < 96) {
        int rr = t / 24, j = t % 24;
        int l = blockIdx.x * 4 + rr;
        float rp = Bih[j] + Wih[j * 17 + 16] * reward[0];
        const float* pr = P + (64 + l) * 8;
        for (int k = 0; k < 8; ++k) rp += Wih[j * 17 + k] * pr[k];
        sGX4[rr][j] = rp;
    }
    __syncthreads();
    int rr = t >> 6, nn = t & 63;
    int l = blockIdx.x * 4 + rr, n = 960 + nn;
    if (!A[(64 + l) * NN + n]) return;
    f32x8 post = ld8(P + n * 8);
    const float* hp;
    if (l < 832 && A[(128 + l) * NN + n]) hp = Uright + ((64 + l) * 64 + nn) * 8;
    else                                  hp = hidden0 + ((64 + l) * NN + n) * 8;
    f32x8 h = ld8(hp);
    f32x8 upd = gru_fast(sWP, sWH, sGX4[rr], sBhh, post, h, lr[0]);
    f32x8 pre = ld8(P + (64 + l) * 8);
    st8(PH + (l * NN + n) * 8, upd * pre);
}

// output-layer synapses (tick1 only): row 960+l, writes PH rows l<64; skip-if-inactive.
__global__ void __launch_bounds__(256, 4)
k_syn_out(const int* __restrict__ A, const float* __restrict__ hidden0,
          const float* __restrict__ P, float* __restrict__ PH,
          float* __restrict__ Uout,
          const float* __restrict__ Wih, const float* __restrict__ Whh,
          const float* __restrict__ Bih, const float* __restrict__ Bhh,
          const float* __restrict__ reward, const float* __restrict__ lr)
{
    int l = blockIdx.x >> 2;
    STAGE_SYN(960 + l);
    int n = ((blockIdx.x & 3) << 8) | threadIdx.x;
    if (!A[(960 + l) * NN + n]) return;
    f32x8 post = ld8(P + n * 8);
    f32x8 h = ld8(hidden0 + ((960 + l) * NN + n) * 8);
    f32x8 upd = gru_fast(sWP, sWH, sGX, sBhh, post, h, lr[0]);
    f32x8 pre = ld8(P + (960 + l) * 8);
    int e = (l * NN + n) * 8;
    st8(PH + e, upd * pre);
    st8(Uout + e, upd);
}

// partial column sums over PH: grid (ncolgroups, 8 rowblocks), 256 thr = 32 cols x 8 dims
__global__ void __launch_bounds__(256)
k_colsum(const float* __restrict__ PH, float* __restrict__ Spart,
         int col_start, int rows_per_block)
{
    int base = (col_start + blockIdx.x * 32) * 8 + threadIdx.x;
    int r0 = blockIdx.y * rows_per_block;
    float acc = 0.f;
    for (int k = 0; k < rows_per_block; ++k)
        acc += PH[(r0 + k) * 8192 + base];
    Spart[blockIdx.y * 8192 + base] = acc;
}

// neuron update: P[col] = tanh( (sum_rb Spart) @ W.T + b )
__global__ void __launch_bounds__(256)
k_neuron(const float* __restrict__ Spart, float* __restrict__ P,
         const float* __restrict__ W, const float* __restrict__ b,
         int col_start)
{
    int gid = blockIdx.x * blockDim.x + threadIdx.x;
    int nl = gid >> 3, j = gid & 7;
    int col = col_start + nl;
    float z = b[j];
#pragma unroll
    for (int d = 0; d < 8; ++d) {
        float a = 0.f;
#pragma unroll
        for (int rb = 0; rb < 8; ++rb) a += Spart[rb * 8192 + col * 8 + d];
        z += a * W[j * 8 + d];
    }
    P[col * 8 + j] = tanhf(z);
}

__global__ void __launch_bounds__(64)
k_argmax(const float* __restrict__ P, float* __restrict__ out)
{
    __shared__ float v[64];
    int t = threadIdx.x;
    v[t] = P[(960 + t) * 8];  // dim 0 of output neurons
    __syncthreads();
    if (t == 0) {
        int best = 0; float bv = v[0];
        for (int j = 1; j < 64; ++j)
            if (v[j] > bv) { bv = v[j]; best = j; }   // strict > = first-index tie-break
        out[0] = (float)best;
    }
}

extern "C" void kernel_launch(void* const* d_in, const int* in_sizes, int n_in,
                              void* d_out, int out_size, void* d_ws, size_t ws_size,
                              hipStream_t stream)
{
    const float* obs      = (const float*)d_in[0];
    const float* reward   = (const float*)d_in[1];
    const int*   A        = (const int*)d_in[2];
    const float* hidden0  = (const float*)d_in[3];
    const float* post0    = (const float*)d_in[4];
    const float* lr       = (const float*)d_in[5];
    const float* fc_in_w  = (const float*)d_in[6];
    const float* fc_in_b  = (const float*)d_in[7];
    const float* fc_hid_w = (const float*)d_in[8];
    const float* fc_hid_b = (const float*)d_in[9];
    const float* fc_out_w = (const float*)d_in[10];
    const float* fc_out_b = (const float*)d_in[11];
    const float* gin_wih  = (const float*)d_in[12];
    const float* gin_whh  = (const float*)d_in[13];
    const float* gin_bih  = (const float*)d_in[14];
    const float* gin_bhh  = (const float*)d_in[15];
    const float* ghid_wih = (const float*)d_in[16];
    const float* ghid_whh = (const float*)d_in[17];
    const float* ghid_bih = (const float*)d_in[18];
    const float* ghid_bhh = (const float*)d_in[19];
    const float* gout_wih = (const float*)d_in[20];
    const float* gout_whh = (const float*)d_in[21];
    const float* gout_bih = (const float*)d_in[22];
    const float* gout_bhh = (const float*)d_in[23];

    float* ws    = (float*)d_ws;
    float* PH    = ws;
    float* Uin   = ws + 7340032;
    float* Utop  = Uin + 524288;
    float* Urt   = Utop + 524288;
    float* Uout  = Urt + 458752;
    float* P     = Uout + 524288;
    float* Spart = P + 8192;

    k_prep<<<32, 256, 0, stream>>>(obs, fc_in_w, fc_in_b, post0, P);

    // ---- tick 1 ----
    k_syn_in<1><<<256, 256, 0, stream>>>(A, hidden0, P, PH, Uin, Utop, Uout,
                                         gin_wih, gin_whh, gin_bih, gin_bhh, reward, lr);
    k_colsum<<<dim3(28, 8), 256, 0, stream>>>(PH, Spart, 64, 8);    // only rows<64 written yet
    k_neuron<<<28, 256, 0, stream>>>(Spart, P, fc_hid_w, fc_hid_b, 64);
    k_syn_hid1<<<3584, 256, 0, stream>>>(A, hidden0, P, PH, Utop, Urt,
                                         ghid_wih, ghid_whh, ghid_bih, ghid_bhh, reward, lr);
    k_colsum<<<dim3(2, 8), 256, 0, stream>>>(PH, Spart, 960, 112);
    k_neuron<<<2, 256, 0, stream>>>(Spart, P, fc_out_w, fc_out_b, 960);
    k_syn_out<<<256, 256, 0, stream>>>(A, hidden0, P, PH, Uout,
                                       gout_wih, gout_whh, gout_bih, gout_bhh, reward, lr);

    // ---- tick 2 (input-neuron update identical to tick1 -> skipped; out-syn dead) ----
    k_syn_in<2><<<256, 256, 0, stream>>>(A, hidden0, P, PH, Uin, Utop, Uout,
                                         gin_wih, gin_whh, gin_bih, gin_bhh, reward, lr);
    k_colsum<<<dim3(28, 8), 256, 0, stream>>>(PH, Spart, 64, 112);
    k_neuron<<<28, 256, 0, stream>>>(Spart, P, fc_hid_w, fc_hid_b, 64);
    k_syn_hid2<<<224, 256, 0, stream>>>(A, hidden0, P, PH, Urt,
                                        ghid_wih, ghid_whh, ghid_bih, ghid_bhh, reward, lr);
    k_colsum<<<dim3(2, 8), 256, 0, stream>>>(PH, Spart, 960, 112);
    k_neuron<<<2, 256, 0, stream>>>(Spart, P, fc_out_w, fc_out_b, 960);

    k_argmax<<<1, 64, 0, stream>>>(P, (float*)d_out);
}

// Round 6
// 76.535 us; speedup vs baseline: 18.9372x; 2.2150x over previous
//
#include <hip/hip_runtime.h>

#define NN 1024

typedef float f32x8 __attribute__((ext_vector_type(8)));

// ---------------- workspace layout (floats) ----------------
// PH     : [896][1024][8] @ 0        (7340032)  cols<64 never written/read
// Uin    : [64][1024][8]  @ 7340032  (524288)
// Utop   : [64][1024][8]  @ 7864320  (524288)
// Urt    : [896][64][8]   @ 8388608  (458752)
// Uout   : [64][1024][8]  @ 8847360  (524288)
// P      : [1024][8]      @ 9371648  (8192)
// GXPin1 : [1024][24]     @ 9379840  (24576)   gin  over P0   (cols 64..960)
// GXPhid1: [1024][24]     @ 9404416  (24576)   ghid over P1   (64..960 + 960..1024)
// GXPout : [1024][24]     @ 9428992  (24576)   gout over P2   (cols 64..960)
// GXPin2 : [1024][24]     @ 9453568  (24576)   gin  over P2   (cols 64..960)
// GXPhid2: [1024][24]     @ 9478144  (24576)   ghid over P3   (cols 960..1024)
// total 9502720 floats = 38.0 MB

__device__ __forceinline__ float sigmoid_f(float x)
{
    return __fdividef(1.f, 1.f + __expf(-x));
}
__device__ __forceinline__ float tanh_f(float x)
{
    float ax = fabsf(x);
    float e  = __expf(-2.f * ax);
    float t  = __fdividef(1.f - e, 1.f + e);
    return copysignf(t, x);
}
__device__ __forceinline__ f32x8 ld8(const float* __restrict__ p) { return *(const f32x8*)p; }
__device__ __forceinline__ void st8(float* __restrict__ p, f32x8 v) { *(f32x8*)p = v; }

// gx = sGX[j] (row part: bias+reward+pre) + gxp[j] (col part, precomputed) ;
// gh = sBhh[j] + Whh[j]·h  (per-edge, irreducible)
__device__ __forceinline__ f32x8 gru_core(const float (*__restrict__ sWH)[8],
                                          const float* __restrict__ sGX,
                                          const float* __restrict__ sBhh,
                                          const float* __restrict__ gxp,
                                          f32x8 h, float lr)
{
    f32x8 gr = ld8(gxp), gz = ld8(gxp + 8), gn = ld8(gxp + 16);
    f32x8 upd;
#pragma unroll
    for (int d = 0; d < 8; ++d) {
        float hr = sBhh[d], hz = sBhh[8 + d], hn = sBhh[16 + d];
#pragma unroll
        for (int k = 0; k < 8; ++k) {
            hr = fmaf(sWH[d][k],      h[k], hr);
            hz = fmaf(sWH[8 + d][k],  h[k], hz);
            hn = fmaf(sWH[16 + d][k], h[k], hn);
        }
        float r  = sigmoid_f(sGX[d] + gr[d] + hr);
        float z  = sigmoid_f(sGX[8 + d] + gz[d] + hz);
        float nv = tanh_f(fmaf(r, hn, sGX[16 + d] + gn[d]));
        float g  = (1.f - z) * nv + z * h[d];
        upd[d] = fmaf(g, lr, h[d]);
    }
    return upd;
}

#define SYN_STAGE(PREROW)                                                               \
    __shared__ float sWH[24][8]; __shared__ float sGX[24]; __shared__ float sBhh[24];   \
    { int t_ = threadIdx.x;                                                             \
      if (t_ < 192) { int j = t_ >> 3, k = t_ & 7; sWH[j][k] = Whh[j * 8 + k]; }        \
      else if (t_ < 216) { int j = t_ - 192;                                            \
        float a = Bih[j] + Wih[j * 17 + 16] * reward[0];                                \
        _Pragma("unroll") for (int k = 0; k < 8; ++k)                                   \
            a = fmaf(Wih[j * 17 + k], P[(PREROW) * 8 + k], a);                          \
        sGX[j] = a; sBhh[j] = Bhh[j]; }                                                 \
      __syncthreads(); }

// P init + GXPin1 (gin over P0, cols 64..960) + GXPhid1 tail (ghid over post0, cols 960..)
__global__ void __launch_bounds__(256)
k_prep(const float* __restrict__ obs, const float* __restrict__ fiw,
       const float* __restrict__ fib, const float* __restrict__ post0,
       float* __restrict__ P, float* __restrict__ GXPin1, float* __restrict__ GXPhid1,
       const float* __restrict__ gin_wih, const float* __restrict__ ghid_wih)
{
    int t = threadIdx.x, b = blockIdx.x;
    int gid = b * 256 + t;
    float pv;
    if (gid < 512) {
        int i = gid >> 3, j = gid & 7;
        float rs = 0.f;
#pragma unroll
        for (int d = 0; d < 8; ++d) rs += fiw[j * 8 + d];
        pv = tanhf(obs[i] * rs + fib[j]);
    } else {
        pv = post0[gid];
    }
    P[gid] = pv;
    __shared__ float sP[256];
    sP[t] = pv;
    __syncthreads();
    int c0 = b * 32;
    const float* W = nullptr; float* dst = nullptr;
    if (c0 >= 64 && c0 < 960) { W = gin_wih;  dst = GXPin1; }
    else if (c0 >= 960)       { W = ghid_wih; dst = GXPhid1; }
    if (dst) {
        for (int v = t; v < 768; v += 256) {
            int c = v / 24, j = v % 24;
            float a = 0.f;
#pragma unroll
            for (int k = 0; k < 8; ++k) a = fmaf(W[j * 17 + 8 + k], sP[c * 8 + k], a);
            dst[(c0 + c) * 24 + j] = a;
        }
    }
}

// input-layer syn: row r=bid>>2 (<64), cols 64..1024. TICK1 zero-fills inactive.
template <int TICK>
__global__ void __launch_bounds__(256, 4)
k_syn_in(const int* __restrict__ A, const float* __restrict__ hidden0,
         const float* __restrict__ P, float* __restrict__ PH,
         float* __restrict__ Uin, const float* __restrict__ Utop,
         const float* __restrict__ Uout, const float* __restrict__ GXP,
         const float* __restrict__ Wih, const float* __restrict__ Whh,
         const float* __restrict__ Bih, const float* __restrict__ Bhh,
         const float* __restrict__ reward, const float* __restrict__ lr)
{
    int r = blockIdx.x >> 2;
    SYN_STAGE(r);
    int n = 64 + ((blockIdx.x & 3) << 8) + threadIdx.x;
    if (n >= NN) return;
    int e = (r * NN + n) * 8;
    if (!A[r * NN + n]) {
        if (TICK == 1) { f32x8 z{}; st8(PH + e, z); }
        return;
    }
    f32x8 h;
    if (TICK == 1) {
        h = ld8(hidden0 + e);
    } else {
        const float* src = Uin + e;                    // m_in active by construction
        if (A[(960 + r) * NN + n])     src = Uout + e; // H write order: out > hid > in
        else if (A[(64 + r) * NN + n]) src = Utop + e;
        h = ld8(src);
    }
    f32x8 upd = gru_core(sWH, sGX, sBhh, GXP + n * 24, h, lr[0]);
    f32x8 pre = ld8(P + r * 8);
    st8(PH + e, upd * pre);
    if (TICK == 1) st8(Uin + e, upd);
}

// hidden syn tick1: row l=bid>>2 (<896), cols 64..1024.
// l<64 skip-if-inactive (preserve in-syn); l>=64 zero-if-inactive.
__global__ void __launch_bounds__(256, 4)
k_syn_hid1(const int* __restrict__ A, const float* __restrict__ hidden0,
           const float* __restrict__ P, float* __restrict__ PH,
           float* __restrict__ Utop, float* __restrict__ Urt,
           const float* __restrict__ GXP,
           const float* __restrict__ Wih, const float* __restrict__ Whh,
           const float* __restrict__ Bih, const float* __restrict__ Bhh,
           const float* __restrict__ reward, const float* __restrict__ lr)
{
    int l = blockIdx.x >> 2;
    SYN_STAGE(64 + l);
    int n = 64 + ((blockIdx.x & 3) << 8) + threadIdx.x;
    if (n >= NN) return;
    int e = (l * NN + n) * 8;
    if (!A[(64 + l) * NN + n]) {
        if (l >= 64) { f32x8 z{}; st8(PH + e, z); }
        return;
    }
    f32x8 h = ld8(hidden0 + ((64 + l) * NN + n) * 8);
    f32x8 upd = gru_core(sWH, sGX, sBhh, GXP + n * 24, h, lr[0]);
    f32x8 pre = ld8(P + (64 + l) * 8);
    st8(PH + e, upd * pre);
    if (l < 64) st8(Utop + e, upd);
    if (n >= 960) st8(Urt + (l * 64 + (n - 960)) * 8, upd);
}

// output syn tick1: row 960+l, writes PH rows l<64; skip-if-inactive.
__global__ void __launch_bounds__(256, 4)
k_syn_out(const int* __restrict__ A, const float* __restrict__ hidden0,
          const float* __restrict__ P, float* __restrict__ PH,
          float* __restrict__ Uout, const float* __restrict__ GXP,
          const float* __restrict__ Wih, const float* __restrict__ Whh,
          const float* __restrict__ Bih, const float* __restrict__ Bhh,
          const float* __restrict__ reward, const float* __restrict__ lr)
{
    int l = blockIdx.x >> 2;
    SYN_STAGE(960 + l);
    int n = 64 + ((blockIdx.x & 3) << 8) + threadIdx.x;
    if (n >= NN) return;
    if (!A[(960 + l) * NN + n]) return;
    f32x8 h = ld8(hidden0 + ((960 + l) * NN + n) * 8);
    f32x8 upd = gru_core(sWH, sGX, sBhh, GXP + n * 24, h, lr[0]);
    f32x8 pre = ld8(P + (960 + l) * 8);
    int e = (l * NN + n) * 8;
    st8(PH + e, upd * pre);
    st8(Uout + e, upd);
}

// hidden syn tick2: rows 0..896, cols 960..1024 only; skip-if-inactive. 4 rows/block.
__global__ void __launch_bounds__(256, 4)
k_syn_hid2(const int* __restrict__ A, const float* __restrict__ hidden0,
           const float* __restrict__ P, float* __restrict__ PH,
           const float* __restrict__ Urt, const float* __restrict__ GXP,
           const float* __restrict__ Wih, const float* __restrict__ Whh,
           const float* __restrict__ Bih, const float* __restrict__ Bhh,
           const float* __restrict__ reward, const float* __restrict__ lr)
{
    __shared__ float sWH[24][8]; __shared__ float sBhh[24]; __shared__ float sGX4[4][24];
    int t = threadIdx.x;
    if (t < 192) { int j = t >> 3, k = t & 7; sWH[j][k] = Whh[j * 8 + k]; }
    else if (t < 216) sBhh[t - 192] = Bhh[t - 192];
    if (t < 96) {
        int rr = t / 24, j = t % 24;
        int l = blockIdx.x * 4 + rr;
        float a = Bih[j] + Wih[j * 17 + 16] * reward[0];
#pragma unroll
        for (int k = 0; k < 8; ++k) a = fmaf(Wih[j * 17 + k], P[(64 + l) * 8 + k], a);
        sGX4[rr][j] = a;
    }
    __syncthreads();
    int rr = t >> 6, nn = t & 63;
    int l = blockIdx.x * 4 + rr, n = 960 + nn;
    if (!A[(64 + l) * NN + n]) return;
    const float* hp = (l < 832 && A[(128 + l) * NN + n]) ? (Urt + ((64 + l) * 64 + nn) * 8)
                                                         : (hidden0 + ((64 + l) * NN + n) * 8);
    f32x8 h = ld8(hp);
    f32x8 upd = gru_core(sWH, sGX4[rr], sBhh, GXP + n * 24, h, lr[0]);
    f32x8 pre = ld8(P + (64 + l) * 8);
    st8(PH + (l * NN + n) * 8, upd * pre);
}

// tick1 hidden neuron: sum PH rows 0..64 (only written rows), cols 64..960,
// fused tanh-neuron + GXP production for the 3 downstream syn kernels.
__global__ void __launch_bounds__(256)
k_sum_hid1(const float* __restrict__ PH, float* __restrict__ P,
           const float* __restrict__ W, const float* __restrict__ b,
           float* __restrict__ GXPhid1, float* __restrict__ GXPout,
           float* __restrict__ GXPin2,
           const float* __restrict__ ghid_wih, const float* __restrict__ gout_wih,
           const float* __restrict__ gin_wih)
{
    int t = threadIdx.x;
    int c0 = 64 + blockIdx.x * 32;
    int base = c0 * 8 + t;
    float acc = 0.f;
    for (int r = 0; r < 64; ++r) acc += PH[r * 8192 + base];
    __shared__ float sS[256];
    sS[t] = acc; __syncthreads();
    int j = t & 7;
    float z = b[j];
#pragma unroll
    for (int d = 0; d < 8; ++d) z = fmaf(sS[(t & ~7) | d], W[j * 8 + d], z);
    float pv = tanhf(z);
    P[base] = pv;
    __shared__ float sP[256];
    sP[t] = pv; __syncthreads();
    for (int v = t; v < 768; v += 256) {
        int c = v / 24, jj = v % 24;
        float a1 = 0.f, a2 = 0.f, a3 = 0.f;
#pragma unroll
        for (int k = 0; k < 8; ++k) {
            float p = sP[c * 8 + k];
            a1 = fmaf(ghid_wih[jj * 17 + 8 + k], p, a1);
            a2 = fmaf(gout_wih[jj * 17 + 8 + k], p, a2);
            a3 = fmaf(gin_wih [jj * 17 + 8 + k], p, a3);
        }
        int o = (c0 + c) * 24 + jj;
        GXPhid1[o] = a1; GXPout[o] = a2; GXPin2[o] = a3;
    }
}

// generic 896-row column sum + neuron (8 cols/block, 512 thr = 8c x 8d x 8 chunks),
// optional fused GXP production.
template <bool DO_GXP>
__global__ void __launch_bounds__(512)
k_sumN(const float* __restrict__ PH, float* __restrict__ P,
       const float* __restrict__ W, const float* __restrict__ b,
       int col0, float* __restrict__ GXPdst, const float* __restrict__ gWih)
{
    int t = threadIdx.x;
    int col = (t >> 3) & 7, dim = t & 7, chunk = t >> 6;
    int gc0 = col0 + blockIdx.x * 8;
    float acc = 0.f;
    int base = (gc0 + col) * 8 + dim;
    for (int r = chunk * 112; r < chunk * 112 + 112; ++r) acc += PH[r * 8192 + base];
    __shared__ float sA[8][64];
    sA[chunk][(col << 3) | dim] = acc;
    __syncthreads();
    __shared__ float sS[64];
    if (t < 64) {
        float s = 0.f;
#pragma unroll
        for (int c = 0; c < 8; ++c) s += sA[c][t];
        sS[t] = s;
    }
    __syncthreads();
    __shared__ float sPn[64];
    if (t < 64) {
        int cl = t >> 3, j = t & 7;
        float z = b[j];
#pragma unroll
        for (int d = 0; d < 8; ++d) z = fmaf(sS[(cl << 3) | d], W[j * 8 + d], z);
        float pv = tanhf(z);
        P[(gc0 + cl) * 8 + j] = pv;
        sPn[t] = pv;
    }
    __syncthreads();
    if (DO_GXP && t < 192) {
        int c = t / 24, j = t % 24;
        float a = 0.f;
#pragma unroll
        for (int k = 0; k < 8; ++k) a = fmaf(gWih[j * 17 + 8 + k], sPn[c * 8 + k], a);
        GXPdst[(gc0 + c) * 24 + j] = a;
    }
}

__global__ void __launch_bounds__(64)
k_argmax(const float* __restrict__ P, float* __restrict__ out)
{
    __shared__ float v[64];
    int t = threadIdx.x;
    v[t] = P[(960 + t) * 8];
    __syncthreads();
    if (t == 0) {
        int best = 0; float bv = v[0];
        for (int j = 1; j < 64; ++j)
            if (v[j] > bv) { bv = v[j]; best = j; }   // strict > = first-index tie-break
        out[0] = (float)best;
    }
}

extern "C" void kernel_launch(void* const* d_in, const int* in_sizes, int n_in,
                              void* d_out, int out_size, void* d_ws, size_t ws_size,
                              hipStream_t stream)
{
    const float* obs      = (const float*)d_in[0];
    const float* reward   = (const float*)d_in[1];
    const int*   A        = (const int*)d_in[2];
    const float* hidden0  = (const float*)d_in[3];
    const float* post0    = (const float*)d_in[4];
    const float* lr       = (const float*)d_in[5];
    const float* fc_in_w  = (const float*)d_in[6];
    const float* fc_in_b  = (const float*)d_in[7];
    const float* fc_hid_w = (const float*)d_in[8];
    const float* fc_hid_b = (const float*)d_in[9];
    const float* fc_out_w = (const float*)d_in[10];
    const float* fc_out_b = (const float*)d_in[11];
    const float* gin_wih  = (const float*)d_in[12];
    const float* gin_whh  = (const float*)d_in[13];
    const float* gin_bih  = (const float*)d_in[14];
    const float* gin_bhh  = (const float*)d_in[15];
    const float* ghid_wih = (const float*)d_in[16];
    const float* ghid_whh = (const float*)d_in[17];
    const float* ghid_bih = (const float*)d_in[18];
    const float* ghid_bhh = (const float*)d_in[19];
    const float* gout_wih = (const float*)d_in[20];
    const float* gout_whh = (const float*)d_in[21];
    const float* gout_bih = (const float*)d_in[22];
    const float* gout_bhh = (const float*)d_in[23];

    float* ws      = (float*)d_ws;
    float* PH      = ws;
    float* Uin     = ws + 7340032;
    float* Utop    = Uin + 524288;
    float* Urt     = Utop + 524288;
    float* Uout    = Urt + 458752;
    float* P       = Uout + 524288;
    float* GXPin1  = P + 8192;
    float* GXPhid1 = GXPin1 + 24576;
    float* GXPout  = GXPhid1 + 24576;
    float* GXPin2  = GXPout + 24576;
    float* GXPhid2 = GXPin2 + 24576;

    k_prep<<<32, 256, 0, stream>>>(obs, fc_in_w, fc_in_b, post0, P,
                                   GXPin1, GXPhid1, gin_wih, ghid_wih);

    // ---- tick 1 ----
    k_syn_in<1><<<256, 256, 0, stream>>>(A, hidden0, P, PH, Uin, Utop, Uout, GXPin1,
                                         gin_wih, gin_whh, gin_bih, gin_bhh, reward, lr);
    k_sum_hid1<<<28, 256, 0, stream>>>(PH, P, fc_hid_w, fc_hid_b,
                                       GXPhid1, GXPout, GXPin2,
                                       ghid_wih, gout_wih, gin_wih);
    k_syn_hid1<<<3584, 256, 0, stream>>>(A, hidden0, P, PH, Utop, Urt, GXPhid1,
                                         ghid_wih, ghid_whh, ghid_bih, ghid_bhh, reward, lr);
    k_sumN<true><<<8, 512, 0, stream>>>(PH, P, fc_out_w, fc_out_b, 960, GXPhid2, ghid_wih);
    k_syn_out<<<256, 256, 0, stream>>>(A, hidden0, P, PH, Uout, GXPout,
                                       gout_wih, gout_whh, gout_bih, gout_bhh, reward, lr);

    // ---- tick 2 (input-neuron update identical to tick1 -> skipped; out-syn dead) ----
    k_syn_in<2><<<256, 256, 0, stream>>>(A, hidden0, P, PH, Uin, Utop, Uout, GXPin2,
                                         gin_wih, gin_whh, gin_bih, gin_bhh, reward, lr);
    k_sumN<false><<<112, 512, 0, stream>>>(PH, P, fc_hid_w, fc_hid_b, 64, nullptr, nullptr);
    k_syn_hid2<<<224, 256, 0, stream>>>(A, hidden0, P, PH, Urt, GXPhid2,
                                        ghid_wih, ghid_whh, ghid_bih, ghid_bhh, reward, lr);
    k_sumN<false><<<8, 512, 0, stream>>>(PH, P, fc_out_w, fc_out_b, 960, nullptr, nullptr);

    k_argmax<<<1, 64, 0, stream>>>(P, (float*)d_out);
}